// Round 4
// baseline (247.172 us; speedup 1.0000x reference)
//
#include <hip/hip_runtime.h>
#include <hip/hip_bf16.h>

typedef float vfloat4 __attribute__((ext_vector_type(4)));

// Quad broadcast via DPP quad_perm (VALU pipe, no LDS/DS traffic).
// Q is the source lane within each group of 4.
template <int Q>
__device__ __forceinline__ float qb(float v) {
    int iv = __float_as_int(v);
    int r  = __builtin_amdgcn_update_dpp(iv, iv, Q * 0x55, 0xF, 0xF, true);
    return __int_as_float(r);
}

template <int Q>
__device__ __forceinline__ float4 qb4(float4 v) {
    float4 r;
    r.x = qb<Q>(v.x);
    r.y = qb<Q>(v.y);
    r.z = qb<Q>(v.z);
    r.w = qb<Q>(v.w);
    return r;
}

// 4 lanes per pose: lane j -> pose p = j>>2, row r = j&3.
// Pose loads + output stores are lane-consecutive float4 (fully coalesced).
// Rodrigues via even-polynomial form: R = I + s~ [w]x + c~ (w w^T - th2 I),
//   s~ = sin(th)/th,  c~ = (1-cos(th))/th^2   (Horner in th2; no sqrt/div/sin/cos).
__global__ __launch_bounds__(256) void se3_compose_kernel(
    const float* __restrict__ xi,
    const float4* __restrict__ poses4,   // flat float4 view, length 4*n
    float* __restrict__ out,             // flat float view, length 16*n
    int n4)                              // = 4*n
{
    int i = blockIdx.x * blockDim.x + threadIdx.x;
    if (i >= n4) return;

    int p = i >> 2;   // pose index
    int r = i & 3;    // my row of the pose / output

    // ---- my pose row: perfectly coalesced float4 (issue first) ----
    float4 pr = poses4[i];

    // ---- load xi[p, 0:6] (quad-redundant; same cache lines within quad) ----
    const float2* x2 = (const float2*)(xi + 6ll * p);
    float2 a  = x2[0];  // t0, t1
    float2 b  = x2[1];  // t2, w0
    float2 cc = x2[2];  // w1, w2
    float t0 = a.x, t1 = a.y, t2 = b.x;
    float w0 = b.y, w1 = cc.x, w2 = cc.y;

    // ---- even-polynomial Rodrigues ----
    float th2 = w0 * w0 + w1 * w1 + w2 * w2;

    // s~ = 1 - th2/6 + th2^2/120 - th2^3/5040
    float hs = fmaf(th2, -1.98412698e-4f, 8.33333333e-3f);
    hs = fmaf(th2, hs, -1.66666667e-1f);
    float st = fmaf(th2, hs, 1.0f);

    // c~ = 1/2 - th2/24 + th2^2/720 - th2^3/40320
    float hc = fmaf(th2, -2.48015873e-5f, 1.38888889e-3f);
    hc = fmaf(th2, hc, -4.16666667e-2f);
    float ct = fmaf(th2, hc, 0.5f);

    float d = fmaf(-ct, th2, 1.0f);   // 1 - c~ th2 (diagonal base)

    float cw0 = ct * w0, cw1 = ct * w1, cw2 = ct * w2;
    float sw0 = st * w0, sw1 = st * w1, sw2 = st * w2;

    float R00 = fmaf(cw0, w0, d);
    float R11 = fmaf(cw1, w1, d);
    float R22 = fmaf(cw2, w2, d);
    float R01 = fmaf(cw0, w1, -sw2);
    float R10 = fmaf(cw0, w1,  sw2);
    float R02 = fmaf(cw0, w2,  sw1);
    float R20 = fmaf(cw0, w2, -sw1);
    float R12 = fmaf(cw1, w2, -sw0);
    float R21 = fmaf(cw1, w2,  sw0);

    // ---- row coefficients: out_r = c0*P0 + c1*P1 + c2*P2 + c3*P3 ----
    float c0 = (r == 0) ? R00 : (r == 1) ? R10 : (r == 2) ? R20 : 0.0f;
    float c1 = (r == 0) ? R01 : (r == 1) ? R11 : (r == 2) ? R21 : 0.0f;
    float c2 = (r == 0) ? R02 : (r == 1) ? R12 : (r == 2) ? R22 : 0.0f;
    float c3 = (r == 0) ? t0  : (r == 1) ? t1  : (r == 2) ? t2  : 1.0f;

    // ---- gather all 4 pose rows from the quad via DPP (VALU, no DS) ----
    float4 P0 = qb4<0>(pr);
    float4 P1 = qb4<1>(pr);
    float4 P2 = qb4<2>(pr);
    float4 P3 = qb4<3>(pr);

    vfloat4 o;
    o.x = fmaf(c3, P3.x, fmaf(c2, P2.x, fmaf(c1, P1.x, c0 * P0.x)));
    o.y = fmaf(c3, P3.y, fmaf(c2, P2.y, fmaf(c1, P1.y, c0 * P0.y)));
    o.z = fmaf(c3, P3.z, fmaf(c2, P2.z, fmaf(c1, P1.z, c0 * P0.z)));
    o.w = fmaf(c3, P3.w, fmaf(c2, P2.w, fmaf(c1, P1.w, c0 * P0.w)));

    // output is never re-read: non-temporal store keeps L3 for the inputs
    vfloat4* O = (vfloat4*)(out + 4ll * i);
    __builtin_nontemporal_store(o, O);
}

extern "C" void kernel_launch(void* const* d_in, const int* in_sizes, int n_in,
                              void* d_out, int out_size, void* d_ws, size_t ws_size,
                              hipStream_t stream) {
    const float*  xi     = (const float*)d_in[0];
    const float4* poses4 = (const float4*)d_in[1];
    float*        out    = (float*)d_out;

    int n  = in_sizes[0] / 6;  // N = 2,000,000
    int n4 = 4 * n;

    const int block = 256;
    const int grid  = (n4 + block - 1) / block;
    se3_compose_kernel<<<grid, block, 0, stream>>>(xi, poses4, out, n4);
}